// Round 15
// baseline (177.817 us; speedup 1.0000x reference)
//
#include <hip/hip_runtime.h>

#define N_NODES 50000
#define N_EDGES 800000
#define IN_F 256
#define OUT_F 128

#define CHUNKS 128
#define EPC (N_EDGES / CHUNKS)   // 6250 edges per chunk
#define BINW (N_NODES / 4)       // 12500 u32 words, 4 x u8 bins each (50 KB LDS)
#define NWORDS (N_NODES / 4)     // 12500 packed node-words
#define RGB 196                  // reduceoff blocks per side: 64 words (256 nodes) each
#define HIST_BLOCKS (2 * CHUNKS) // 256
#define CPW8 (CHUNKS / 8)        // 16 chunks per wave (8 waves @ 512 thr)

#define GEMMF_BLOCKS 196         // 256 rows each -> 50176 >= 50000
#define GEMM_K1 98               // GEMM half in K1 (rows 0..25088)
#define GEMM_K2 98               // GEMM half in K2 (rows 25088..50176)
#define HEPC (EPC / 2)           // 3125 edges per scat block (half chunk)

typedef __attribute__((ext_vector_type(8))) short short8;
typedef __attribute__((ext_vector_type(4))) float float4_t;

// float -> bf16 round-to-nearest-even
__device__ __forceinline__ short f2bf(float f) {
  unsigned u = __builtin_bit_cast(unsigned, f);
  u = u + 0x7FFFu + ((u >> 16) & 1u);
  return (short)(u >> 16);
}

__device__ __forceinline__ float bflo(unsigned u) {
  return __builtin_bit_cast(float, u << 16);
}
__device__ __forceinline__ float bfhi(unsigned u) {
  return __builtin_bit_cast(float, u & 0xFFFF0000u);
}

// h column layout (R14): logical col n = t*16+m stored at PHYSICAL p = m*8+t.
// GEMM epilogue writes one short8 (16B) per (r,i); agg un-permutes at out/bias.

// ---- shared GEMM block body (R14-verified): 256 rows per block index gb ----
// R15: GEMM is split 98+98 across K1 (hist shadow) and K2 (reduceoff shadow)
// so the whole dependency-free GEMM hides under the critical chain.
__device__ __forceinline__ void gemm_block(int gb, int tid,
                                           const float* __restrict__ feat,
                                           const float* __restrict__ W,
                                           unsigned short* __restrict__ h,
                                           uint4* smem4) {
  short* wl = (short*)smem4;
#pragma unroll
  for (int i = 0; i < 64; ++i) {
    int idx = i * 512 + tid;
    int k = idx >> 7, n = idx & 127;
    int s = k >> 5, q = (k >> 3) & 3, j = k & 7;
    int tt = n >> 4, m = n & 15;
    wl[((s * 8 + tt) * 64 + q * 16 + m) * 8 + j] = f2bf(W[idx]);
  }
  __syncthreads();

  int w = tid >> 6, l = tid & 63;
  int m = l & 15, q = l >> 4;
  long base = (long)gb * 256 + w * 32;

  float4_t acc[2][8];
#pragma unroll
  for (int r = 0; r < 2; ++r)
#pragma unroll
    for (int to = 0; to < 8; ++to) acc[r][to] = (float4_t)(0.0f);

  long row0 = base + m;
  long row1 = base + 16 + m;
  long r0c = row0 < N_NODES - 1 ? row0 : N_NODES - 1;
  long r1c = row1 < N_NODES - 1 ? row1 : N_NODES - 1;
  const float* a0p = feat + (size_t)r0c * IN_F;
  const float* a1p = feat + (size_t)r1c * IN_F;
  const short8* wl8 = (const short8*)smem4;

#pragma unroll
  for (int s = 0; s < 8; ++s) {
    int k0 = s * 32 + q * 8;
    float4_t av0a = *(const float4_t*)(a0p + k0);
    float4_t av0b = *(const float4_t*)(a0p + k0 + 4);
    float4_t av1a = *(const float4_t*)(a1p + k0);
    float4_t av1b = *(const float4_t*)(a1p + k0 + 4);
    short8 fa0, fa1;
#pragma unroll
    for (int i = 0; i < 4; ++i) {
      fa0[i] = f2bf(av0a[i]);
      fa0[i + 4] = f2bf(av0b[i]);
      fa1[i] = f2bf(av1a[i]);
      fa1[i + 4] = f2bf(av1b[i]);
    }
#pragma unroll
    for (int to = 0; to < 8; ++to) {
      short8 fb = wl8[(s * 8 + to) * 64 + l];
      acc[0][to] = __builtin_amdgcn_mfma_f32_16x16x32_bf16(fa0, fb, acc[0][to], 0, 0, 0);
      acc[1][to] = __builtin_amdgcn_mfma_f32_16x16x32_bf16(fa1, fb, acc[1][to], 0, 0, 0);
    }
  }

  // Epilogue: permuted-h layout -> one short8 (16B) store per (r,i).
#pragma unroll
  for (int r = 0; r < 2; ++r) {
#pragma unroll
    for (int i = 0; i < 4; ++i) {
      long row = base + r * 16 + q * 4 + i;
      if (row < N_NODES) {
        short8 hv;
#pragma unroll
        for (int to = 0; to < 8; ++to) hv[to] = f2bf(acc[r][to][i]);
        *(short8*)(h + (size_t)row * OUT_F + m * 8) = hv;
      }
    }
  }
}

// ---- K1: hist(256) || GEMM-half-1(98) ----
// R7 lesson: global-atomic hist/scatter is 3-6x SLOWER. R8: NT stores regress.
__global__ __launch_bounds__(512) void histgemm_kernel(const int* __restrict__ src,
                                                       const int* __restrict__ dst,
                                                       unsigned char* __restrict__ pdst8,
                                                       unsigned char* __restrict__ psrc8,
                                                       unsigned char* __restrict__ rank8,
                                                       int* __restrict__ cursor,
                                                       const float* __restrict__ feat,
                                                       const float* __restrict__ W,
                                                       unsigned short* __restrict__ h) {
  __shared__ uint4 smem4[4096];  // 64 KB: hist bins (50 KB) or W-bf16 (64 KB)
  int b = blockIdx.x;
  int tid = threadIdx.x;

  if (b >= HIST_BLOCKS) {  // GEMM half 1: rows [0, 25088)
    gemm_block(b - HIST_BLOCKS, tid, feat, W, h, smem4);
    return;
  }

  unsigned* bins = (unsigned*)smem4;
  if (b == 0 && tid == 0) *cursor = 0;  // consumed by K2's reduceoff blocks
  int hs = b >> 7;
  int c = b & 127;
  uint4* b4 = (uint4*)bins;
  for (int j = tid; j < BINW / 4; j += 512) b4[j] = (uint4){0u, 0u, 0u, 0u};
  __syncthreads();
  const int* key = hs ? src : dst;
  int e0 = c * EPC;

  auto process = [&](int v, int eI) {
    unsigned sh = (v & 3) * 8;
    unsigned old = atomicAdd(&bins[v >> 2], 1u << sh);
    if (!hs) rank8[eI] = (unsigned char)((old >> sh) & 0xFFu);
  };

  // 3 full tiles of 2048 + tail of 106 (EPC = 6250)
#pragma unroll 2
  for (int tile = 0; tile < 3; ++tile) {
    int i = tile * 2048 + tid;
    int k0 = key[e0 + i];
    int k1 = key[e0 + i + 512];
    int k2 = key[e0 + i + 1024];
    int k3 = key[e0 + i + 1536];
    process(k0, e0 + i);
    process(k1, e0 + i + 512);
    process(k2, e0 + i + 1024);
    process(k3, e0 + i + 1536);
  }
  {
    int i = 6144 + tid;
    if (i < EPC) process(key[e0 + i], e0 + i);
  }
  __syncthreads();
  uint4* p128 = (uint4*)((hs ? psrc8 : pdst8) + (size_t)c * N_NODES);  // rows 16B-aligned
  const uint4* s128 = (const uint4*)smem4;
  for (int j = tid; j < BINW / 4; j += 512) p128[j] = s128[j];
}

// ---- K2: reduceoff(392) || GEMM-half-2(98) ----
__global__ __launch_bounds__(512) void redgemm_kernel(const float* __restrict__ feat,
                                                      const float* __restrict__ W,
                                                      unsigned short* __restrict__ h,
                                                      const unsigned char* __restrict__ pdst8,
                                                      const unsigned char* __restrict__ psrc8,
                                                      unsigned char* __restrict__ delta8,
                                                      int* __restrict__ cnt,
                                                      int* __restrict__ row_start,
                                                      int* __restrict__ cursor,
                                                      float* __restrict__ norm) {
  __shared__ uint4 smem4[4096];  // 64 KB: W-bf16 (GEMM) or tot[8][64] (reduceoff)
  int b = blockIdx.x;
  int tid = threadIdx.x;

  if (b >= 2 * RGB) {  // GEMM half 2: rows [25088, 50176)
    gemm_block(GEMM_K1 + (b - 2 * RGB), tid, feat, W, h, smem4);
    return;
  }

  // ---- reduceoff path: 8 waves x 16 chunks, packed-byte prefix ----
  int side = b >= RGB ? 1 : 0;
  int g = b - side * RGB;
  int w = tid >> 6, l = tid & 63;
  int wd = g * 64 + l;
  bool ok = wd < NWORDS;
  int wdc = ok ? wd : NWORDS - 1;  // clamp for safe addressing
  const unsigned* P = (const unsigned*)(side == 0 ? pdst8 : psrc8);
  unsigned(*tot)[64] = (unsigned(*)[64])smem4;

  unsigned vals[CPW8];
  unsigned s = 0;
#pragma unroll
  for (int i = 0; i < CPW8; ++i) {
    vals[i] = P[(size_t)(w * CPW8 + i) * NWORDS + wdc];
    s += vals[i];
  }
  tot[w][l] = s;
  __syncthreads();

  if (side == 0) {
    unsigned base = 0;
#pragma unroll
    for (int w2 = 0; w2 < 8; ++w2)
      if (w2 < w) base += tot[w2][l];
    unsigned run = base;
    unsigned* D = (unsigned*)delta8;
    if (ok) {
#pragma unroll
      for (int i = 0; i < CPW8; ++i) {
        D[(size_t)(w * CPW8 + i) * NWORDS + wd] = run;
        run += vals[i];
      }
    }
    if (w == 0) {
      unsigned ftot = 0;
#pragma unroll
      for (int w2 = 0; w2 < 8; ++w2) ftot += tot[w2][l];
      if (!ok) ftot = 0;
      int c0 = ftot & 255, c1 = (ftot >> 8) & 255, c2 = (ftot >> 16) & 255, c3 = ftot >> 24;
      int T = c0 + c1 + c2 + c3;
      int x = T;
#pragma unroll
      for (int off = 1; off < 64; off <<= 1) {
        int y = __shfl_up(x, off);
        if (l >= off) x += y;
      }
      int waveTotal = __shfl(x, 63);
      int sb = 0;
      if (l == 63) sb = atomicAdd(cursor, waveTotal);
      sb = __shfl(sb, 63);
      int E = sb + x - T;
      if (ok) {
        int4 cv = {c0, c1, c2, c3};
        int4 rv = {E, E + c0, E + c0 + c1, E + c0 + c1 + c2};
        ((int4*)cnt)[wd] = cv;
        ((int4*)row_start)[wd] = rv;
      }
    }
  } else {
    if (w == 0 && ok) {
      unsigned ftot = 0;
#pragma unroll
      for (int w2 = 0; w2 < 8; ++w2) ftot += tot[w2][l];
      float4 nv;
      int d0 = ftot & 255, d1 = (ftot >> 8) & 255, d2 = (ftot >> 16) & 255, d3 = (int)(ftot >> 24);
      nv.x = 1.0f / (float)(d0 > 1 ? d0 : 1);
      nv.y = 1.0f / (float)(d1 > 1 ? d1 : 1);
      nv.z = 1.0f / (float)(d2 > 1 ? d2 : 1);
      nv.w = 1.0f / (float)(d3 > 1 ? d3 : 1);
      ((float4*)norm)[wd] = nv;
    }
  }
}

// ---- K3: scatter with LDS-staged delta8 row (verified R13) ----
__global__ __launch_bounds__(512) void scat_kernel(const int* __restrict__ src,
                                                   const int* __restrict__ dst,
                                                   const int* __restrict__ row_start,
                                                   const unsigned char* __restrict__ delta8,
                                                   const unsigned char* __restrict__ rank8,
                                                   int* __restrict__ eidx) {
  __shared__ uint4 dl4[N_NODES / 16];  // 50 KB: delta8 row for this chunk
  int b = blockIdx.x;
  int tid = threadIdx.x;
  int c = b >> 1, hb = b & 1;
  const uint4* rowp = (const uint4*)(delta8 + (size_t)c * N_NODES);  // 16B-aligned
  for (int j = tid; j < N_NODES / 16; j += 512) dl4[j] = rowp[j];
  __syncthreads();
  const unsigned char* dl = (const unsigned char*)dl4;
  int e0 = c * EPC + hb * HEPC;

  // 3125 edges: 6 full strides of 512 + tail of 53
  int dsts[6], rks[6], srcs[6], rss[6];
#pragma unroll
  for (int k = 0; k < 6; ++k) {
    int e = e0 + k * 512 + tid;
    dsts[k] = dst[e];
    rks[k] = (int)rank8[e];
  }
#pragma unroll
  for (int k = 0; k < 6; ++k) rss[k] = row_start[dsts[k]];  // 6 L2 reads in flight
#pragma unroll
  for (int k = 0; k < 6; ++k) srcs[k] = src[e0 + k * 512 + tid];
#pragma unroll
  for (int k = 0; k < 6; ++k) {
    int pos = rss[k] + (int)dl[dsts[k]] + rks[k];
    eidx[pos] = srcs[k];
  }
  if (tid < HEPC - 6 * 512) {  // tail: 53 edges
    int e = e0 + 3072 + tid;
    int d = dst[e];
    int pos = row_start[d] + (int)dl[d] + (int)rank8[e];
    eidx[pos] = src[e];
  }
}

// ---- agg: uint4 gathers over permuted h (R9 gather + R14 un-permute) ----
__global__ __launch_bounds__(256) void agg_kernel(const unsigned short* __restrict__ h,
                                                  const int* __restrict__ row_start,
                                                  const int* __restrict__ cnt,
                                                  const int* __restrict__ eidx,
                                                  const float* __restrict__ norm,
                                                  const float* __restrict__ bias,
                                                  float* __restrict__ out) {
  int w = threadIdx.x >> 6, l = threadIdx.x & 63;
  int d = blockIdx.x * 4 + w;  // grid 12500 -> exactly 50000
  int rs = row_start[d], re = rs + cnt[d];
  const uint4* __restrict__ hu4 = (const uint4*)h;  // 16 uint4 per 256B row
  int rowsel = l >> 4;  // 0..3: which of 4 rows in flight
  int cp = l & 15;      // uint4 index within row -> physical cols 8*cp .. 8*cp+7
  float a0 = 0.f, a1 = 0.f, a2 = 0.f, a3 = 0.f, a4 = 0.f, a5 = 0.f, a6 = 0.f, a7 = 0.f;

  auto acc8 = [&](uint4 v, float nm) {
    a0 = fmaf(bflo(v.x), nm, a0); a1 = fmaf(bfhi(v.x), nm, a1);
    a2 = fmaf(bflo(v.y), nm, a2); a3 = fmaf(bfhi(v.y), nm, a3);
    a4 = fmaf(bflo(v.z), nm, a4); a5 = fmaf(bfhi(v.z), nm, a5);
    a6 = fmaf(bflo(v.w), nm, a6); a7 = fmaf(bfhi(v.w), nm, a7);
  };

  for (int bse = rs; bse < re; bse += 64) {
    int n = re - bse; if (n > 64) n = 64;
    int e = (l < n) ? eidx[bse + l] : 0;
    int quarter = (n + 3) >> 2;  // ceil(n/4) row-group steps
    int j = 0;
    for (; j + 4 <= quarter; j += 4) {  // 16 rows per iteration, 4 x 16B gathers/lane
      int i0 = 4 * j + rowsel;
      int s0 = __shfl(e, i0);
      int s1 = __shfl(e, i0 + 4);
      int s2 = __shfl(e, i0 + 8);
      int s3 = __shfl(e, i0 + 12);
      uint4 v0 = hu4[(size_t)s0 * 16 + cp];
      uint4 v1 = hu4[(size_t)s1 * 16 + cp];
      uint4 v2 = hu4[(size_t)s2 * 16 + cp];
      uint4 v3 = hu4[(size_t)s3 * 16 + cp];
      float nm0 = norm[s0], nm1 = norm[s1], nm2 = norm[s2], nm3 = norm[s3];
      if (i0 >= n) v0 = (uint4){0u, 0u, 0u, 0u};
      if (i0 + 4 >= n) v1 = (uint4){0u, 0u, 0u, 0u};
      if (i0 + 8 >= n) v2 = (uint4){0u, 0u, 0u, 0u};
      if (i0 + 12 >= n) v3 = (uint4){0u, 0u, 0u, 0u};
      acc8(v0, nm0);
      acc8(v1, nm1);
      acc8(v2, nm2);
      acc8(v3, nm3);
    }
    for (; j < quarter; ++j) {
      int i0 = 4 * j + rowsel;
      int s0 = __shfl(e, i0);
      uint4 v0 = hu4[(size_t)s0 * 16 + cp];
      float nm0 = norm[s0];
      if (i0 >= n) v0 = (uint4){0u, 0u, 0u, 0u};
      acc8(v0, nm0);
    }
  }
  // sum the 4 rowsel groups: lanes {cp, cp+16, cp+32, cp+48}
  a0 += __shfl_xor(a0, 16); a1 += __shfl_xor(a1, 16);
  a2 += __shfl_xor(a2, 16); a3 += __shfl_xor(a3, 16);
  a4 += __shfl_xor(a4, 16); a5 += __shfl_xor(a5, 16);
  a6 += __shfl_xor(a6, 16); a7 += __shfl_xor(a7, 16);
  a0 += __shfl_xor(a0, 32); a1 += __shfl_xor(a1, 32);
  a2 += __shfl_xor(a2, 32); a3 += __shfl_xor(a3, 32);
  a4 += __shfl_xor(a4, 32); a5 += __shfl_xor(a5, 32);
  a6 += __shfl_xor(a6, 32); a7 += __shfl_xor(a7, 32);
  if (rowsel == 0) {
    // un-permute: a_j holds physical 8*cp+j = logical col j*16+cp.
    float av[8] = {a0, a1, a2, a3, a4, a5, a6, a7};
    float* op = out + (size_t)d * OUT_F;
#pragma unroll
    for (int j = 0; j < 8; ++j) {
      int col = j * 16 + cp;  // 16 lanes -> 64B contiguous per j
      op[col] = av[j] + bias[col];
    }
  }
}

extern "C" void kernel_launch(void* const* d_in, const int* in_sizes, int n_in,
                              void* d_out, int out_size, void* d_ws, size_t ws_size,
                              hipStream_t stream) {
  const float* feat = (const float*)d_in[0];
  const float* weight = (const float*)d_in[1];
  const float* bias = (const float*)d_in[2];
  const int* src = (const int*)d_in[3];
  const int* dst = (const int*)d_in[4];
  float* out = (float*)d_out;

  char* ws = (char*)d_ws;
  size_t off = 0;
  auto alloc = [&](size_t bytes) -> void* {
    void* p = ws + off;
    off += (bytes + 511) & ~(size_t)511;
    return p;
  };
  int* cursor = (int*)alloc(4);
  int* cnt = (int*)alloc(N_NODES * 4);
  int* row_start = (int*)alloc(N_NODES * 4);
  float* norm = (float*)alloc(N_NODES * 4);
  int* eidx = (int*)alloc(N_EDGES * 4);
  unsigned short* h = (unsigned short*)alloc((size_t)N_NODES * OUT_F * 2);
  unsigned char* pdst8 = (unsigned char*)alloc((size_t)CHUNKS * N_NODES);
  unsigned char* psrc8 = (unsigned char*)alloc((size_t)CHUNKS * N_NODES);
  unsigned char* delta8 = (unsigned char*)alloc((size_t)CHUNKS * N_NODES);
  unsigned char* rank8 = (unsigned char*)alloc((size_t)N_EDGES);
  (void)off; (void)ws_size; (void)in_sizes; (void)n_in; (void)out_size;

  hipLaunchKernelGGL(histgemm_kernel, dim3(HIST_BLOCKS + GEMM_K1), dim3(512), 0, stream,
                     src, dst, pdst8, psrc8, rank8, cursor, feat, weight, h);
  hipLaunchKernelGGL(redgemm_kernel, dim3(2 * RGB + GEMM_K2), dim3(512), 0, stream,
                     feat, weight, h, pdst8, psrc8, delta8, cnt, row_start, cursor, norm);
  hipLaunchKernelGGL(scat_kernel, dim3(2 * CHUNKS), dim3(512), 0, stream,
                     src, dst, row_start, delta8, rank8, eidx);
  hipLaunchKernelGGL(agg_kernel, dim3(N_NODES / 4), dim3(256), 0, stream,
                     h, row_start, cnt, eidx, norm, bias, out);
}

// Round 16
// 161.067 us; speedup vs baseline: 1.1040x; 1.1040x over previous
//
#include <hip/hip_runtime.h>

#define N_NODES 50000
#define N_EDGES 800000
#define IN_F 256
#define OUT_F 128

#define CHUNKS 128
#define EPC (N_EDGES / CHUNKS)   // 6250 edges per chunk
#define BINW (N_NODES / 4)       // 12500 u32 words, 4 x u8 bins each (50 KB LDS)
#define NWORDS (N_NODES / 4)     // 12500 packed node-words
#define RGB 196                  // reduceoff blocks per side: 64 words (256 nodes) each
#define HIST_BLOCKS (2 * CHUNKS) // 256
#define CPW8 (CHUNKS / 8)        // 16 chunks per wave (8 waves @ 512 thr)

#define GEMMF_BLOCKS 196         // 256 rows each -> 50176 >= 50000
#define HEPC (EPC / 2)           // 3125 edges per scat block (half chunk)

typedef __attribute__((ext_vector_type(8))) short short8;
typedef __attribute__((ext_vector_type(4))) float float4_t;

// float -> bf16 round-to-nearest-even
__device__ __forceinline__ short f2bf(float f) {
  unsigned u = __builtin_bit_cast(unsigned, f);
  u = u + 0x7FFFu + ((u >> 16) & 1u);
  return (short)(u >> 16);
}

__device__ __forceinline__ float bflo(unsigned u) {
  return __builtin_bit_cast(float, u << 16);
}
__device__ __forceinline__ float bfhi(unsigned u) {
  return __builtin_bit_cast(float, u & 0xFFFF0000u);
}

// ---- K1: histograms only (dst side writes per-edge rank too) ----
// R7 lesson: global-atomic hist/scatter is 3-6x SLOWER (cross-XCD hot lines).
// R8 lesson: nontemporal stores regress. Plain LDS-binned hist.
// R15 lesson: hist GATES the chain — don't union its LDS to 64KB or pair it
// with GEMM blocks (occupancy 3->2/CU + VMEM contention cost more than hidden).
__global__ __launch_bounds__(512) void hist_kernel(const int* __restrict__ src,
                                                   const int* __restrict__ dst,
                                                   unsigned char* __restrict__ pdst8,
                                                   unsigned char* __restrict__ psrc8,
                                                   unsigned char* __restrict__ rank8,
                                                   int* __restrict__ cursor) {
  __shared__ unsigned bins[BINW];
  int b = blockIdx.x;
  int tid = threadIdx.x;
  if (b == 0 && tid == 0) *cursor = 0;  // consumed by K2's reduceoff blocks
  int hs = b >> 7;
  int c = b & 127;
  uint4* b4 = (uint4*)bins;
  for (int j = tid; j < BINW / 4; j += 512) b4[j] = (uint4){0u, 0u, 0u, 0u};
  __syncthreads();
  const int* key = hs ? src : dst;
  int e0 = c * EPC;

  auto process = [&](int v, int eI) {
    unsigned sh = (v & 3) * 8;
    unsigned old = atomicAdd(&bins[v >> 2], 1u << sh);
    if (!hs) rank8[eI] = (unsigned char)((old >> sh) & 0xFFu);
  };

  // 3 full tiles of 2048 + tail of 106 (EPC = 6250)
#pragma unroll 2
  for (int tile = 0; tile < 3; ++tile) {
    int i = tile * 2048 + tid;
    int k0 = key[e0 + i];
    int k1 = key[e0 + i + 512];
    int k2 = key[e0 + i + 1024];
    int k3 = key[e0 + i + 1536];
    process(k0, e0 + i);
    process(k1, e0 + i + 512);
    process(k2, e0 + i + 1024);
    process(k3, e0 + i + 1536);
  }
  {
    int i = 6144 + tid;
    if (i < EPC) process(key[e0 + i], e0 + i);
  }
  __syncthreads();
  uint4* p128 = (uint4*)((hs ? psrc8 : pdst8) + (size_t)c * N_NODES);  // rows 16B-aligned
  const uint4* s128 = (const uint4*)bins;
  for (int j = tid; j < BINW / 4; j += 512) p128[j] = s128[j];
}

// ---- K2: GEMM || reduceoff (verified R12 overlap pair, best structure) ----
// blocks [0,196): GEMM, 256 rows each. blocks [196,588): reduceoff, 8 waves x
// 16 chunks each; side = (b-196)/196, g = remainder.
__global__ __launch_bounds__(512) void gemmred_kernel(const float* __restrict__ feat,
                                                      const float* __restrict__ W,
                                                      unsigned short* __restrict__ h,
                                                      const unsigned char* __restrict__ pdst8,
                                                      const unsigned char* __restrict__ psrc8,
                                                      unsigned char* __restrict__ delta8,
                                                      int* __restrict__ cnt,
                                                      int* __restrict__ row_start,
                                                      int* __restrict__ cursor,
                                                      float* __restrict__ norm) {
  __shared__ uint4 smem4[4096];  // 64 KB: W-bf16 (GEMM) or tot[8][64] (reduceoff)
  int b = blockIdx.x;
  int tid = threadIdx.x;

  if (b < GEMMF_BLOCKS) {
    // ---- GEMM path (verified R5/R10 structure) ----
    short* wl = (short*)smem4;
#pragma unroll
    for (int i = 0; i < 64; ++i) {
      int idx = i * 512 + tid;
      int k = idx >> 7, n = idx & 127;
      int s = k >> 5, q = (k >> 3) & 3, j = k & 7;
      int tt = n >> 4, m = n & 15;
      wl[((s * 8 + tt) * 64 + q * 16 + m) * 8 + j] = f2bf(W[idx]);
    }
    __syncthreads();

    int w = tid >> 6, l = tid & 63;
    int m = l & 15, q = l >> 4;
    long base = (long)b * 256 + w * 32;

    float4_t acc[2][8];
#pragma unroll
    for (int r = 0; r < 2; ++r)
#pragma unroll
      for (int to = 0; to < 8; ++to) acc[r][to] = (float4_t)(0.0f);

    long row0 = base + m;
    long row1 = base + 16 + m;
    long r0c = row0 < N_NODES - 1 ? row0 : N_NODES - 1;
    long r1c = row1 < N_NODES - 1 ? row1 : N_NODES - 1;
    const float* a0p = feat + (size_t)r0c * IN_F;
    const float* a1p = feat + (size_t)r1c * IN_F;
    const short8* wl8 = (const short8*)smem4;

#pragma unroll
    for (int s = 0; s < 8; ++s) {
      int k0 = s * 32 + q * 8;
      float4_t av0a = *(const float4_t*)(a0p + k0);
      float4_t av0b = *(const float4_t*)(a0p + k0 + 4);
      float4_t av1a = *(const float4_t*)(a1p + k0);
      float4_t av1b = *(const float4_t*)(a1p + k0 + 4);
      short8 fa0, fa1;
#pragma unroll
      for (int i = 0; i < 4; ++i) {
        fa0[i] = f2bf(av0a[i]);
        fa0[i + 4] = f2bf(av0b[i]);
        fa1[i] = f2bf(av1a[i]);
        fa1[i + 4] = f2bf(av1b[i]);
      }
#pragma unroll
      for (int to = 0; to < 8; ++to) {
        short8 fb = wl8[(s * 8 + to) * 64 + l];
        acc[0][to] = __builtin_amdgcn_mfma_f32_16x16x32_bf16(fa0, fb, acc[0][to], 0, 0, 0);
        acc[1][to] = __builtin_amdgcn_mfma_f32_16x16x32_bf16(fa1, fb, acc[1][to], 0, 0, 0);
      }
    }

    // C/D layout: col = lane&15 (=m), row = q*4 + i. Norm deferred to agg.
#pragma unroll
    for (int r = 0; r < 2; ++r) {
#pragma unroll
      for (int i = 0; i < 4; ++i) {
        long row = base + r * 16 + q * 4 + i;
        if (row < N_NODES) {
          size_t ho = (size_t)row * OUT_F;
#pragma unroll
          for (int to = 0; to < 8; ++to) {
            h[ho + to * 16 + m] = (unsigned short)f2bf(acc[r][to][i]);
          }
        }
      }
    }
    return;
  }

  // ---- reduceoff path: 8 waves x 16 chunks, packed-byte prefix ----
  int rb = b - GEMMF_BLOCKS;
  int side = rb >= RGB ? 1 : 0;
  int g = rb - side * RGB;
  int w = tid >> 6, l = tid & 63;
  int wd = g * 64 + l;
  bool ok = wd < NWORDS;
  int wdc = ok ? wd : NWORDS - 1;  // clamp for safe addressing
  const unsigned* P = (const unsigned*)(side == 0 ? pdst8 : psrc8);
  unsigned(*tot)[64] = (unsigned(*)[64])smem4;

  unsigned vals[CPW8];
  unsigned s = 0;
#pragma unroll
  for (int i = 0; i < CPW8; ++i) {
    vals[i] = P[(size_t)(w * CPW8 + i) * NWORDS + wdc];
    s += vals[i];
  }
  tot[w][l] = s;
  __syncthreads();

  if (side == 0) {
    unsigned base = 0;
#pragma unroll
    for (int w2 = 0; w2 < 8; ++w2)
      if (w2 < w) base += tot[w2][l];
    unsigned run = base;
    unsigned* D = (unsigned*)delta8;
    if (ok) {
#pragma unroll
      for (int i = 0; i < CPW8; ++i) {
        D[(size_t)(w * CPW8 + i) * NWORDS + wd] = run;
        run += vals[i];
      }
    }
    if (w == 0) {
      unsigned ftot = 0;
#pragma unroll
      for (int w2 = 0; w2 < 8; ++w2) ftot += tot[w2][l];
      if (!ok) ftot = 0;
      int c0 = ftot & 255, c1 = (ftot >> 8) & 255, c2 = (ftot >> 16) & 255, c3 = ftot >> 24;
      int T = c0 + c1 + c2 + c3;
      int x = T;
#pragma unroll
      for (int off = 1; off < 64; off <<= 1) {
        int y = __shfl_up(x, off);
        if (l >= off) x += y;
      }
      int waveTotal = __shfl(x, 63);
      int sb = 0;
      if (l == 63) sb = atomicAdd(cursor, waveTotal);
      sb = __shfl(sb, 63);
      int E = sb + x - T;
      if (ok) {
        int4 cv = {c0, c1, c2, c3};
        int4 rv = {E, E + c0, E + c0 + c1, E + c0 + c1 + c2};
        ((int4*)cnt)[wd] = cv;
        ((int4*)row_start)[wd] = rv;
      }
    }
  } else {
    if (w == 0 && ok) {
      unsigned ftot = 0;
#pragma unroll
      for (int w2 = 0; w2 < 8; ++w2) ftot += tot[w2][l];
      float4 nv;
      int d0 = ftot & 255, d1 = (ftot >> 8) & 255, d2 = (ftot >> 16) & 255, d3 = (int)(ftot >> 24);
      nv.x = 1.0f / (float)(d0 > 1 ? d0 : 1);
      nv.y = 1.0f / (float)(d1 > 1 ? d1 : 1);
      nv.z = 1.0f / (float)(d2 > 1 ? d2 : 1);
      nv.w = 1.0f / (float)(d3 > 1 ? d3 : 1);
      ((float4*)norm)[wd] = nv;
    }
  }
}

// ---- K3: scatter with LDS-staged delta8 row (verified R13, best) ----
// All 6250 edges of a chunk read the SAME 50KB delta8 row -> stage it in LDS
// (coalesced), making the random byte-read ~free. 256 blocks x 512 thr.
// row_start random L2 reads are 6-deep hand-unrolled for MLP.
__global__ __launch_bounds__(512) void scat_kernel(const int* __restrict__ src,
                                                   const int* __restrict__ dst,
                                                   const int* __restrict__ row_start,
                                                   const unsigned char* __restrict__ delta8,
                                                   const unsigned char* __restrict__ rank8,
                                                   int* __restrict__ eidx) {
  __shared__ uint4 dl4[N_NODES / 16];  // 50 KB: delta8 row for this chunk
  int b = blockIdx.x;
  int tid = threadIdx.x;
  int c = b >> 1, hb = b & 1;
  const uint4* rowp = (const uint4*)(delta8 + (size_t)c * N_NODES);  // 16B-aligned
  for (int j = tid; j < N_NODES / 16; j += 512) dl4[j] = rowp[j];
  __syncthreads();
  const unsigned char* dl = (const unsigned char*)dl4;
  int e0 = c * EPC + hb * HEPC;

  // 3125 edges: 6 full strides of 512 + tail of 53
  int dsts[6], rks[6], srcs[6], rss[6];
#pragma unroll
  for (int k = 0; k < 6; ++k) {
    int e = e0 + k * 512 + tid;
    dsts[k] = dst[e];
    rks[k] = (int)rank8[e];
  }
#pragma unroll
  for (int k = 0; k < 6; ++k) rss[k] = row_start[dsts[k]];  // 6 L2 reads in flight
#pragma unroll
  for (int k = 0; k < 6; ++k) srcs[k] = src[e0 + k * 512 + tid];
#pragma unroll
  for (int k = 0; k < 6; ++k) {
    int pos = rss[k] + (int)dl[dsts[k]] + rks[k];
    eidx[pos] = srcs[k];
  }
  if (tid < HEPC - 6 * 512) {  // tail: 53 edges
    int e = e0 + 3072 + tid;
    int d = dst[e];
    int pos = row_start[d] + (int)dl[d] + (int)rank8[e];
    eidx[pos] = src[e];
  }
}

// ---- agg: uint4 (16B) gathers — 16 lanes/row, 4 rows x 4-deep (R9 verified).
// At L3 random-line service ceiling (~5.8 TB/s effective); parked.
__global__ __launch_bounds__(256) void agg_kernel(const unsigned short* __restrict__ h,
                                                  const int* __restrict__ row_start,
                                                  const int* __restrict__ cnt,
                                                  const int* __restrict__ eidx,
                                                  const float* __restrict__ norm,
                                                  const float* __restrict__ bias,
                                                  float* __restrict__ out) {
  int w = threadIdx.x >> 6, l = threadIdx.x & 63;
  int d = blockIdx.x * 4 + w;  // grid 12500 -> exactly 50000
  int rs = row_start[d], re = rs + cnt[d];
  const uint4* __restrict__ hu4 = (const uint4*)h;  // 16 uint4 per 256B row
  int rowsel = l >> 4;  // 0..3: which of 4 rows in flight
  int cp = l & 15;      // uint4 index within row -> cols 8*cp .. 8*cp+7
  float a0 = 0.f, a1 = 0.f, a2 = 0.f, a3 = 0.f, a4 = 0.f, a5 = 0.f, a6 = 0.f, a7 = 0.f;

  auto acc8 = [&](uint4 v, float nm) {
    a0 = fmaf(bflo(v.x), nm, a0); a1 = fmaf(bfhi(v.x), nm, a1);
    a2 = fmaf(bflo(v.y), nm, a2); a3 = fmaf(bfhi(v.y), nm, a3);
    a4 = fmaf(bflo(v.z), nm, a4); a5 = fmaf(bfhi(v.z), nm, a5);
    a6 = fmaf(bflo(v.w), nm, a6); a7 = fmaf(bfhi(v.w), nm, a7);
  };

  for (int bse = rs; bse < re; bse += 64) {
    int n = re - bse; if (n > 64) n = 64;
    int e = (l < n) ? eidx[bse + l] : 0;
    int quarter = (n + 3) >> 2;  // ceil(n/4) row-group steps
    int j = 0;
    for (; j + 4 <= quarter; j += 4) {  // 16 rows per iteration, 4 x 16B gathers/lane
      int i0 = 4 * j + rowsel;
      int s0 = __shfl(e, i0);
      int s1 = __shfl(e, i0 + 4);
      int s2 = __shfl(e, i0 + 8);
      int s3 = __shfl(e, i0 + 12);
      uint4 v0 = hu4[(size_t)s0 * 16 + cp];
      uint4 v1 = hu4[(size_t)s1 * 16 + cp];
      uint4 v2 = hu4[(size_t)s2 * 16 + cp];
      uint4 v3 = hu4[(size_t)s3 * 16 + cp];
      float nm0 = norm[s0], nm1 = norm[s1], nm2 = norm[s2], nm3 = norm[s3];
      if (i0 >= n) v0 = (uint4){0u, 0u, 0u, 0u};
      if (i0 + 4 >= n) v1 = (uint4){0u, 0u, 0u, 0u};
      if (i0 + 8 >= n) v2 = (uint4){0u, 0u, 0u, 0u};
      if (i0 + 12 >= n) v3 = (uint4){0u, 0u, 0u, 0u};
      acc8(v0, nm0);
      acc8(v1, nm1);
      acc8(v2, nm2);
      acc8(v3, nm3);
    }
    for (; j < quarter; ++j) {
      int i0 = 4 * j + rowsel;
      int s0 = __shfl(e, i0);
      uint4 v0 = hu4[(size_t)s0 * 16 + cp];
      float nm0 = norm[s0];
      if (i0 >= n) v0 = (uint4){0u, 0u, 0u, 0u};
      acc8(v0, nm0);
    }
  }
  // sum the 4 rowsel groups: lanes {cp, cp+16, cp+32, cp+48}
  a0 += __shfl_xor(a0, 16); a1 += __shfl_xor(a1, 16);
  a2 += __shfl_xor(a2, 16); a3 += __shfl_xor(a3, 16);
  a4 += __shfl_xor(a4, 16); a5 += __shfl_xor(a5, 16);
  a6 += __shfl_xor(a6, 16); a7 += __shfl_xor(a7, 16);
  a0 += __shfl_xor(a0, 32); a1 += __shfl_xor(a1, 32);
  a2 += __shfl_xor(a2, 32); a3 += __shfl_xor(a3, 32);
  a4 += __shfl_xor(a4, 32); a5 += __shfl_xor(a5, 32);
  a6 += __shfl_xor(a6, 32); a7 += __shfl_xor(a7, 32);
  if (rowsel == 0) {
    float4 b0 = ((const float4*)bias)[2 * cp];
    float4 b1 = ((const float4*)bias)[2 * cp + 1];
    float4 o0, o1;
    o0.x = a0 + b0.x; o0.y = a1 + b0.y; o0.z = a2 + b0.z; o0.w = a3 + b0.w;
    o1.x = a4 + b1.x; o1.y = a5 + b1.y; o1.z = a6 + b1.z; o1.w = a7 + b1.w;
    float4* op = (float4*)(out + (size_t)d * OUT_F + 8 * cp);
    op[0] = o0;
    op[1] = o1;
  }
}

extern "C" void kernel_launch(void* const* d_in, const int* in_sizes, int n_in,
                              void* d_out, int out_size, void* d_ws, size_t ws_size,
                              hipStream_t stream) {
  const float* feat = (const float*)d_in[0];
  const float* weight = (const float*)d_in[1];
  const float* bias = (const float*)d_in[2];
  const int* src = (const int*)d_in[3];
  const int* dst = (const int*)d_in[4];
  float* out = (float*)d_out;

  char* ws = (char*)d_ws;
  size_t off = 0;
  auto alloc = [&](size_t bytes) -> void* {
    void* p = ws + off;
    off += (bytes + 511) & ~(size_t)511;
    return p;
  };
  int* cursor = (int*)alloc(4);
  int* cnt = (int*)alloc(N_NODES * 4);
  int* row_start = (int*)alloc(N_NODES * 4);
  float* norm = (float*)alloc(N_NODES * 4);
  int* eidx = (int*)alloc(N_EDGES * 4);
  unsigned short* h = (unsigned short*)alloc((size_t)N_NODES * OUT_F * 2);
  unsigned char* pdst8 = (unsigned char*)alloc((size_t)CHUNKS * N_NODES);
  unsigned char* psrc8 = (unsigned char*)alloc((size_t)CHUNKS * N_NODES);
  unsigned char* delta8 = (unsigned char*)alloc((size_t)CHUNKS * N_NODES);
  unsigned char* rank8 = (unsigned char*)alloc((size_t)N_EDGES);
  (void)off; (void)ws_size; (void)in_sizes; (void)n_in; (void)out_size;

  hipLaunchKernelGGL(hist_kernel, dim3(HIST_BLOCKS), dim3(512), 0, stream,
                     src, dst, pdst8, psrc8, rank8, cursor);
  hipLaunchKernelGGL(gemmred_kernel, dim3(GEMMF_BLOCKS + 2 * RGB), dim3(512), 0, stream,
                     feat, weight, h, pdst8, psrc8, delta8, cnt, row_start, cursor, norm);
  hipLaunchKernelGGL(scat_kernel, dim3(2 * CHUNKS), dim3(512), 0, stream,
                     src, dst, row_start, delta8, rank8, eidx);
  hipLaunchKernelGGL(agg_kernel, dim3(N_NODES / 4), dim3(256), 0, stream,
                     h, row_start, cnt, eidx, norm, bias, out);
}